// Round 12
// baseline (510.352 us; speedup 1.0000x reference)
//
#include <hip/hip_runtime.h>
#include <hip/hip_bf16.h>
#include <math.h>

// ProteinGAT: 2x GATConv + fc head, fp32 accuracy.
// GEMMs on MFMA via bf16x3 split; A operands are PRE-SPLIT into bf16 hi/lo
// planes (x via k_split_a; layer-1 aggregate writes planes directly), so the
// GEMM K-loop stages pure 16B copies (no per-step fp32->bf16 VALU work).
// GEMM outputs only hi/lo bf16 planes: node_attn reconstructs h = hi+lo
// (2^-17 error), aggregation gathers the hi plane (== old bf16 payload).
// CSR build: count captures per-edge rank (atomic return) so fill is atomic-free.
// fc head fused into the layer-2 aggregate epilogue (8-lane shfl reduce).

#define DEVFN __device__ __forceinline__

typedef __attribute__((ext_vector_type(8))) short short8;
typedef __attribute__((ext_vector_type(4))) float f32x4;

DEVFN float wave_reduce_sum(float v) {
    for (int off = 32; off; off >>= 1) v += __shfl_xor(v, off);
    return v;
}

DEVFN ushort f2bf_rne(float f) {
    unsigned u = __float_as_uint(f);
    unsigned r = (u + 0x7fff + ((u >> 16) & 1)) >> 16;
    return (ushort)r;
}
DEVFN float bf2f(ushort b) { return __uint_as_float(((unsigned)b) << 16); }

// ---------------- init: zero degree counters + mean accumulator ----------------
__global__ void k_init(int* __restrict__ deg, float* __restrict__ meanbuf, int N) {
    int i = blockIdx.x * blockDim.x + threadIdx.x;
    if (i < N) deg[i] = 0;
    if (i < 2) meanbuf[i] = 0.f;
}

// ---------------- CSR count (by dst), capturing per-edge rank ----------------
__global__ void k_count(const int* __restrict__ dstrow, int* __restrict__ deg,
                        int* __restrict__ rank, int E, int Et) {
    int t = blockIdx.x * blockDim.x + threadIdx.x;
    if (t >= Et) return;
    int d = (t < E) ? dstrow[t] : (t - E);   // self loops appended
    rank[t] = atomicAdd(&deg[d], 1);
}

// ---------------- mean(edge_attr) over E rows (2 columns), few blocks ----------------
__global__ void k_mean(const float* __restrict__ ea, float* __restrict__ meanbuf, int E) {
    __shared__ float s0s[4], s1s[4];
    float s0 = 0.f, s1 = 0.f;
    for (int i = blockIdx.x * blockDim.x + threadIdx.x; i < E; i += gridDim.x * blockDim.x) {
        float2 v = reinterpret_cast<const float2*>(ea)[i];
        s0 += v.x; s1 += v.y;
    }
    s0 = wave_reduce_sum(s0);
    s1 = wave_reduce_sum(s1);
    int lane = threadIdx.x & 63, w = threadIdx.x >> 6;
    if (lane == 0) { s0s[w] = s0; s1s[w] = s1; }
    __syncthreads();
    if (threadIdx.x == 0) {
        float a = 0.f, b = 0.f;
        for (int i = 0; i < (int)(blockDim.x >> 6); i++) { a += s0s[i]; b += s1s[i]; }
        atomicAdd(&meanbuf[0], a);
        atomicAdd(&meanbuf[1], b);
    }
}

__global__ void k_scan_block(const int* __restrict__ deg, int* __restrict__ rowptr,
                             int* __restrict__ bsums, int N) {
    __shared__ int sd[1024];
    int i = blockIdx.x * 1024 + threadIdx.x;
    sd[threadIdx.x] = (i < N) ? deg[i] : 0;
    __syncthreads();
    for (int off = 1; off < 1024; off <<= 1) {
        int x = (threadIdx.x >= off) ? sd[threadIdx.x - off] : 0;
        __syncthreads();
        sd[threadIdx.x] += x;
        __syncthreads();
    }
    if (i < N) rowptr[i + 1] = sd[threadIdx.x];   // inclusive within block
    if (threadIdx.x == 1023) bsums[blockIdx.x] = sd[1023];
}

__global__ void k_scan_bsums(const int* __restrict__ bsums, int* __restrict__ boffs, int nb) {
    if (threadIdx.x == 0 && blockIdx.x == 0) {
        int run = 0;
        for (int b = 0; b < nb; b++) { boffs[b] = run; run += bsums[b]; }
    }
}

__global__ void k_scan_finalize(int* __restrict__ rowptr, const int* __restrict__ boffs, int N) {
    int i = blockIdx.x * blockDim.x + threadIdx.x;
    if (i < N) rowptr[i + 1] += boffs[i >> 10];
    if (i == 0) rowptr[0] = 0;
}

// ---------------- fill: atomic-free scatter via rowptr[d] + rank[t] ----------------
__global__ void k_fill(const int* __restrict__ srcrow, const int* __restrict__ dstrow,
                       const int* __restrict__ rowptr, const int* __restrict__ rank,
                       int* __restrict__ srcid, float2* __restrict__ ea_csr,
                       const float* __restrict__ ea, const float* __restrict__ meanbuf,
                       float invE, int E, int Et) {
    int t = blockIdx.x * blockDim.x + threadIdx.x;
    if (t >= Et) return;
    int d, s; float2 ev;
    if (t < E) {
        d = dstrow[t]; s = srcrow[t];
        ev = reinterpret_cast<const float2*>(ea)[t];
    } else {
        d = t - E; s = t - E;
        ev = make_float2(meanbuf[0] * invE, meanbuf[1] * invE);
    }
    int pos = rowptr[d] + rank[t];
    srcid[pos] = s;
    ea_csr[pos] = ev;
}

// ---------------- collapse We (2 x H*64) against att_e (H x 64) -> M[2][H] ----------------
template <int H>
__global__ void k_collapse(const float* __restrict__ We, const float* __restrict__ att_e,
                           float* __restrict__ M) {
    int t = threadIdx.x;            // 2*H*64 threads
    int lane = t & 63, w = t >> 6;
    int d = w / H, h = w % H;
    float v = We[(d * H + h) * 64 + lane] * att_e[h * 64 + lane];
    v = wave_reduce_sum(v);
    if (lane == 0) M[d * H + h] = v;
}

// ---------------- W split: [K][Nc] fp32 -> hiT/loT [Nc][Kpad] bf16 ----------------
__global__ void k_split_wT(const float* __restrict__ W, ushort* __restrict__ hiT,
                           ushort* __restrict__ loT, int K, int Nc, int Kpad) {
    int c = blockIdx.x;
    for (int k = threadIdx.x; k < Kpad; k += blockDim.x) {
        float v = (k < K) ? W[(size_t)k * Nc + c] : 0.f;
        ushort h = f2bf_rne(v);
        ushort l = f2bf_rne(v - bf2f(h));
        hiT[(size_t)c * Kpad + k] = h;
        loT[(size_t)c * Kpad + k] = l;
    }
}

// ---------------- A split: [N][K] fp32 -> hi/lo [N][Kpad] bf16 (no transpose) ----------------
__global__ void k_split_a(const float* __restrict__ A, ushort* __restrict__ Ah,
                          ushort* __restrict__ Al, int K, int Kpad) {
    int row = blockIdx.x;
    for (int k = threadIdx.x; k < Kpad; k += blockDim.x) {
        float v = (k < K) ? A[(size_t)row * K + k] : 0.f;
        ushort h = f2bf_rne(v);
        Ah[(size_t)row * Kpad + k] = h;
        Al[(size_t)row * Kpad + k] = f2bf_rne(v - bf2f(h));
    }
}

// ---------------- MFMA GEMM (bf16x3, pre-split A): Chi/Clo[M,ldc] = A @ B ----------------
// A hi/lo planes [.][Kpad]; B hi/lo transposed [n][Kpad]. Staging = 16B copies.
// Output: bf16 hi/lo planes only (no fp32 C).
// MFMA 16x16x32 bf16: A/B frag lane l: row/col = l&15, k = (l>>4)*8 + j;
// C/D: col = lane&15, row = (lane>>4)*4 + reg   [verified m89/m91].
template <int MI, int NI>
__global__ __launch_bounds__(256) void k_gemm_pre(const ushort* __restrict__ Agh,
                                                  const ushort* __restrict__ Agl,
                                                  const ushort* __restrict__ BhT,
                                                  const ushort* __restrict__ BlT,
                                                  ushort* __restrict__ Ch,
                                                  ushort* __restrict__ Cl,
                                                  int M, int Kpad, int ldc) {
    constexpr int BM = 32 * MI, BN = 32 * NI;
    constexpr int LDA = 40;   // ushorts per LDS row (32 + 8 pad, 16B-aligned rows)
    __shared__ __align__(16) ushort Ah[BM * LDA];
    __shared__ __align__(16) ushort Al[BM * LDA];
    __shared__ __align__(16) ushort Bh[BN * LDA];
    __shared__ __align__(16) ushort Bl[BN * LDA];

    int tid = threadIdx.x, lane = tid & 63, wid = tid >> 6;
    int wr = wid >> 1, wc = wid & 1;
    int bm = blockIdx.x * BM, bn = blockIdx.y * BN;

    f32x4 acc[MI][NI];
#pragma unroll
    for (int mi = 0; mi < MI; ++mi)
#pragma unroll
        for (int ni = 0; ni < NI; ++ni) acc[mi][ni] = (f32x4){0.f, 0.f, 0.f, 0.f};

    int steps = Kpad / 32;
    for (int s = 0; s < steps; ++s) {
        int k0 = s * 32;
        __syncthreads();
        // ---- stage A: BM rows x 4 chunks of 16B, both planes ----
#pragma unroll
        for (int j = 0; j < (BM * 4) / 256; ++j) {
            int slot = tid + 256 * j;
            int row = slot >> 2, ch = slot & 3;
            size_t g = (size_t)(bm + row) * Kpad + k0 + ch * 8;
            *reinterpret_cast<float4*>(&Ah[row * LDA + ch * 8]) =
                *reinterpret_cast<const float4*>(&Agh[g]);
            *reinterpret_cast<float4*>(&Al[row * LDA + ch * 8]) =
                *reinterpret_cast<const float4*>(&Agl[g]);
        }
        // ---- stage B: BN rows x 4 chunks of 16B, both planes ----
#pragma unroll
        for (int j = 0; j < (BN * 4) / 256; ++j) {
            int slot = tid + 256 * j;
            int n = slot >> 2, ch = slot & 3;
            size_t g = (size_t)(bn + n) * Kpad + k0 + ch * 8;
            *reinterpret_cast<float4*>(&Bh[n * LDA + ch * 8]) =
                *reinterpret_cast<const float4*>(&BhT[g]);
            *reinterpret_cast<float4*>(&Bl[n * LDA + ch * 8]) =
                *reinterpret_cast<const float4*>(&BlT[g]);
        }
        __syncthreads();
        // ---- fragments + 3*MI*NI MFMAs ----
        int kg = (lane >> 4) * 8;
        int am = wr * (MI * 16) + (lane & 15);
        int bc = wc * (NI * 16) + (lane & 15);
        short8 ah[MI], al[MI], bh[NI], bl[NI];
#pragma unroll
        for (int mi = 0; mi < MI; ++mi) {
            ah[mi] = *reinterpret_cast<const short8*>(&Ah[(am + mi * 16) * LDA + kg]);
            al[mi] = *reinterpret_cast<const short8*>(&Al[(am + mi * 16) * LDA + kg]);
        }
#pragma unroll
        for (int ni = 0; ni < NI; ++ni) {
            bh[ni] = *reinterpret_cast<const short8*>(&Bh[(bc + ni * 16) * LDA + kg]);
            bl[ni] = *reinterpret_cast<const short8*>(&Bl[(bc + ni * 16) * LDA + kg]);
        }
#pragma unroll
        for (int mi = 0; mi < MI; ++mi)
#pragma unroll
            for (int ni = 0; ni < NI; ++ni) {
                acc[mi][ni] = __builtin_amdgcn_mfma_f32_16x16x32_bf16(ah[mi], bh[ni], acc[mi][ni], 0, 0, 0);
                acc[mi][ni] = __builtin_amdgcn_mfma_f32_16x16x32_bf16(ah[mi], bl[ni], acc[mi][ni], 0, 0, 0);
                acc[mi][ni] = __builtin_amdgcn_mfma_f32_16x16x32_bf16(al[mi], bh[ni], acc[mi][ni], 0, 0, 0);
            }
    }
    // ---- epilogue: bf16 hi/lo planes ----
#pragma unroll
    for (int mi = 0; mi < MI; ++mi) {
        int row0 = bm + wr * (MI * 16) + mi * 16 + ((lane >> 4) << 2);
#pragma unroll
        for (int ni = 0; ni < NI; ++ni) {
            int col = bn + wc * (NI * 16) + ni * 16 + (lane & 15);
            f32x4 v = acc[mi][ni];
#pragma unroll
            for (int r = 0; r < 4; ++r)
                if (row0 + r < M) {
                    ushort hb = f2bf_rne(v[r]);
                    Ch[(size_t)(row0 + r) * ldc + col] = hb;
                    Cl[(size_t)(row0 + r) * ldc + col] = f2bf_rne(v[r] - bf2f(hb));
                }
        }
    }
}

// ---------------- per-node attention coefficients from hi/lo planes ----------------
template <int H>
__global__ void k_node_attn2(const ushort* __restrict__ hh, const ushort* __restrict__ hl,
                             const float* __restrict__ att_src,
                             const float* __restrict__ att_dst, float* __restrict__ asrc,
                             float* __restrict__ adst, int N) {
    constexpr int HC = H * 64;
    constexpr int NPB = 256 / HC;
    int local = threadIdx.x % HC;
    int n = blockIdx.x * NPB + threadIdx.x / HC;
    if (n >= N) return;
    size_t idx = (size_t)n * HC + local;
    float v = bf2f(hh[idx]) + bf2f(hl[idx]);   // h to 2^-17 rel
    float s = v * att_src[local];
    float d = v * att_dst[local];
    for (int off = 32; off; off >>= 1) { s += __shfl_xor(s, off); d += __shfl_xor(d, off); }
    if ((local & 63) == 0) {
        int hhid = local >> 6;
        asrc[n * H + hhid] = s;
        adst[n * H + hhid] = d;
    }
}

// ---------------- softmax over incoming edges: one wave per dst node ----------------
template <int H>
__global__ void k_attn(const int* __restrict__ rowptr, const int* __restrict__ srcid,
                       const float2* __restrict__ ea_csr, const float* __restrict__ asrc,
                       const float* __restrict__ adst, const float* __restrict__ M,
                       float* __restrict__ attn, float* __restrict__ dinv, int N) {
    int lane = threadIdx.x & 63;
    int n = blockIdx.x * 4 + (threadIdx.x >> 6);
    if (n >= N) return;
    int start = rowptr[n];
    int items = (rowptr[n + 1] - start) * H;
    int h = lane % H;   // 64 % H == 0 -> constant per lane
    float ad = adst[n * H + h];
    float m0 = M[h], m1 = M[H + h];

    float mx = -1e30f;
    for (int i = lane; i < items; i += 64) {
        int p = start + i / H;
        int s = srcid[p];
        float2 ev = ea_csr[p];
        float al = asrc[s * H + h] + ad + ev.x * m0 + ev.y * m1;
        al = (al > 0.f) ? al : 0.2f * al;
        attn[(size_t)start * H + i] = al;   // == attn[p*H + i%H], CSR-linear
        mx = fmaxf(mx, al);
    }
    for (int off = H; off < 64; off <<= 1) mx = fmaxf(mx, __shfl_xor(mx, off));

    float ss = 0.f;
    for (int i = lane; i < items; i += 64) {
        float ex = expf(attn[(size_t)start * H + i] - mx);
        attn[(size_t)start * H + i] = ex;
        ss += ex;
    }
    for (int off = H; off < 64; off <<= 1) ss += __shfl_xor(ss, off);
    if (lane < H) dinv[n * H + h] = 1.f / (ss + 1e-16f);
}

// ---------------- layer-1 aggregation: gather hi plane, write hi/lo planes + ELU ----------------
template <int H>
__global__ void k_aggregate_planes(const int* __restrict__ rowptr, const int* __restrict__ srcid,
                                   const float* __restrict__ attn, const float* __restrict__ dinv,
                                   const ushort* __restrict__ hbf, const float* __restrict__ bias,
                                   ushort* __restrict__ outh, ushort* __restrict__ outl, int N) {
    constexpr int HC = H * 64;
    constexpr int LPN = HC / 8;            // lanes per node (8 bf16 = 16B per lane)
    constexpr int NPB = 256 / LPN;
    int li = threadIdx.x % LPN;
    int n = blockIdx.x * NPB + threadIdx.x / LPN;
    if (n >= N) return;
    int hh = li >> 3;                       // (li*8)/64
    const short8* h8 = reinterpret_cast<const short8*>(hbf);
    int start = rowptr[n], end = rowptr[n + 1];
    float acc[8];
#pragma unroll
    for (int j = 0; j < 8; ++j) acc[j] = 0.f;
    int p = start;
    for (; p + 3 < end; p += 4) {
        int s0 = srcid[p], s1 = srcid[p + 1], s2 = srcid[p + 2], s3 = srcid[p + 3];
        float w0 = attn[p * H + hh], w1 = attn[(p + 1) * H + hh];
        float w2 = attn[(p + 2) * H + hh], w3 = attn[(p + 3) * H + hh];
        short8 v0 = h8[(size_t)s0 * LPN + li];
        short8 v1 = h8[(size_t)s1 * LPN + li];
        short8 v2 = h8[(size_t)s2 * LPN + li];
        short8 v3 = h8[(size_t)s3 * LPN + li];
#pragma unroll
        for (int j = 0; j < 8; ++j)
            acc[j] += w0 * bf2f((ushort)v0[j]) + w1 * bf2f((ushort)v1[j]) +
                      w2 * bf2f((ushort)v2[j]) + w3 * bf2f((ushort)v3[j]);
    }
    for (; p < end; ++p) {
        int s = srcid[p];
        float w = attn[p * H + hh];
        short8 v = h8[(size_t)s * LPN + li];
#pragma unroll
        for (int j = 0; j < 8; ++j) acc[j] += w * bf2f((ushort)v[j]);
    }
    float inv = dinv[n * H + hh];
    const float4* b4 = reinterpret_cast<const float4*>(bias);
    float4 ba = b4[li * 2], bb = b4[li * 2 + 1];
    float bv[8] = {ba.x, ba.y, ba.z, ba.w, bb.x, bb.y, bb.z, bb.w};
    short8 oh, ol;
#pragma unroll
    for (int j = 0; j < 8; ++j) {
        float r = acc[j] * inv + bv[j];
        r = (r > 0.f) ? r : expm1f(r);      // ELU (layer 1 only)
        ushort hb = f2bf_rne(r);
        oh[j] = (short)hb;
        ol[j] = (short)f2bf_rne(r - bf2f(hb));
    }
    reinterpret_cast<short8*>(outh)[(size_t)n * LPN + li] = oh;
    reinterpret_cast<short8*>(outl)[(size_t)n * LPN + li] = ol;
}

// ---------------- layer-2 aggregate (H=1) with fused fc head ----------------
// 8 lanes per node (8 channels each); after normalize+bias, each lane forms a
// partial dot with Wf and a 3-step shfl_xor tree (1,2,4) reduces within the
// 8-lane group. Lanes of a node are consecutive, never straddle groups.
__global__ void k_aggregate_fc(const int* __restrict__ rowptr, const int* __restrict__ srcid,
                               const float* __restrict__ attn, const float* __restrict__ dinv,
                               const ushort* __restrict__ hbf, const float* __restrict__ bias,
                               const float* __restrict__ Wf, const float* __restrict__ bf,
                               float* __restrict__ out, int N) {
    constexpr int LPN = 8;
    int li = threadIdx.x % LPN;
    int n = blockIdx.x * 32 + threadIdx.x / LPN;
    if (n >= N) return;
    const short8* h8 = reinterpret_cast<const short8*>(hbf);
    int start = rowptr[n], end = rowptr[n + 1];
    float acc[8];
#pragma unroll
    for (int j = 0; j < 8; ++j) acc[j] = 0.f;
    int p = start;
    for (; p + 3 < end; p += 4) {
        int s0 = srcid[p], s1 = srcid[p + 1], s2 = srcid[p + 2], s3 = srcid[p + 3];
        float w0 = attn[p], w1 = attn[p + 1], w2 = attn[p + 2], w3 = attn[p + 3];
        short8 v0 = h8[(size_t)s0 * LPN + li];
        short8 v1 = h8[(size_t)s1 * LPN + li];
        short8 v2 = h8[(size_t)s2 * LPN + li];
        short8 v3 = h8[(size_t)s3 * LPN + li];
#pragma unroll
        for (int j = 0; j < 8; ++j)
            acc[j] += w0 * bf2f((ushort)v0[j]) + w1 * bf2f((ushort)v1[j]) +
                      w2 * bf2f((ushort)v2[j]) + w3 * bf2f((ushort)v3[j]);
    }
    for (; p < end; ++p) {
        int s = srcid[p];
        float w = attn[p];
        short8 v = h8[(size_t)s * LPN + li];
#pragma unroll
        for (int j = 0; j < 8; ++j) acc[j] += w * bf2f((ushort)v[j]);
    }
    float inv = dinv[n];
    const float4* b4 = reinterpret_cast<const float4*>(bias);
    const float4* w4 = reinterpret_cast<const float4*>(Wf);
    float4 ba = b4[li * 2], bb = b4[li * 2 + 1];
    float4 wa = w4[li * 2], wb = w4[li * 2 + 1];
    float bv[8] = {ba.x, ba.y, ba.z, ba.w, bb.x, bb.y, bb.z, bb.w};
    float wv[8] = {wa.x, wa.y, wa.z, wa.w, wb.x, wb.y, wb.z, wb.w};
    float partial = 0.f;
#pragma unroll
    for (int j = 0; j < 8; ++j) partial += (acc[j] * inv + bv[j]) * wv[j];
    partial += __shfl_xor(partial, 1);
    partial += __shfl_xor(partial, 2);
    partial += __shfl_xor(partial, 4);
    if (li == 0) out[n] = partial + bf[0];
}

extern "C" void kernel_launch(void* const* d_in, const int* in_sizes, int n_in,
                              void* d_out, int out_size, void* d_ws, size_t ws_size,
                              hipStream_t stream) {
    const float* x        = (const float*)d_in[0];
    const float* ea       = (const float*)d_in[1];
    const int*   ei       = (const int*)d_in[2];
    const float* W1       = (const float*)d_in[3];
    const float* att_src1 = (const float*)d_in[4];
    const float* att_dst1 = (const float*)d_in[5];
    const float* We1      = (const float*)d_in[6];
    const float* att_e1   = (const float*)d_in[7];
    const float* b1       = (const float*)d_in[8];
    const float* W2       = (const float*)d_in[9];
    const float* att_src2 = (const float*)d_in[10];
    const float* att_dst2 = (const float*)d_in[11];
    const float* We2      = (const float*)d_in[12];
    const float* att_e2   = (const float*)d_in[13];
    const float* b2       = (const float*)d_in[14];
    const float* Wf       = (const float*)d_in[15];
    const float* bf       = (const float*)d_in[16];

    const int IN_DIM = 329;
    const int K1PAD = 352;                 // 11 * 32
    int N  = in_sizes[0] / IN_DIM;
    int E  = in_sizes[1] / 2;
    int Et = E + N;
    const int* srcrow = ei;
    const int* dstrow = ei + E;

    int gM1  = (N + 127) / 128;            // GEMM1 BM=128
    int gM2  = (N + 63) / 64;              // GEMM2 BM=64
    int Mpad = gM1 * 128;                  // >= gM2*64; pads A-plane reads

    // ---- workspace carve ----
    char* p = (char*)d_ws;
    size_t used = 0;
    auto alloc = [&](size_t bytes) -> void* {
        void* r = p;
        size_t pad = (bytes + 255) & ~(size_t)255;
        p += pad; used += pad;
        return r;
    };
    // bufA: xh/xl [Mpad][352] during layer 1; reused as aggh/aggl [Mpad][256]
    ushort* bufA   = (ushort*)alloc((size_t)Mpad * K1PAD * 2 * 2);
    ushort* xh     = bufA;
    ushort* xl     = bufA + (size_t)Mpad * K1PAD;
    ushort* aggh   = bufA;                                  // after GEMM1 done with x
    ushort* aggl   = bufA + (size_t)Mpad * 256;
    // bufB: h1h/h1l [N][256]; reused as h2h/h2l [N][64]
    ushort* bufB   = (ushort*)alloc((size_t)N * 256 * 2 * 2);
    ushort* h1h    = bufB;
    ushort* h1l    = bufB + (size_t)N * 256;
    ushort* h2h    = bufB;                                  // after aggregate<4> done with h1
    ushort* h2l    = bufB + (size_t)N * 64;
    float*  asrc   = (float*)alloc((size_t)N * 4 * 4);
    float*  adst   = (float*)alloc((size_t)N * 4 * 4);
    float*  dinv   = (float*)alloc((size_t)N * 4 * 4);
    float*  attn   = (float*)alloc((size_t)Et * 4 * 4);   // logits -> exp, CSR order, both layers
    float2* ea_csr = (float2*)alloc((size_t)Et * 8);
    int*    srcid  = (int*)alloc((size_t)Et * 4);
    int*    rank   = (int*)alloc((size_t)Et * 4);         // per-edge rank within dst row
    ushort* w1hT   = (ushort*)alloc((size_t)256 * K1PAD * 2);
    ushort* w1lT   = (ushort*)alloc((size_t)256 * K1PAD * 2);
    ushort* w2hT   = (ushort*)alloc((size_t)64 * 256 * 2);
    ushort* w2lT   = (ushort*)alloc((size_t)64 * 256 * 2);
    float*  M1     = (float*)alloc(256);
    float*  M2     = (float*)alloc(256);
    float*  meanbuf= (float*)alloc(256);
    int*    rowptr = (int*)alloc((size_t)(N + 1) * 4);
    int*    deg    = (int*)alloc((size_t)N * 4);
    int*    bsums  = (int*)alloc(1024);
    int*    boffs  = (int*)alloc(1024);
    if (used > ws_size) return;  // workspace too small -> fail loudly via wrong output

    int gN  = (N + 255) / 256;
    int gEt = (Et + 255) / 256;
    int nb  = (N + 1023) / 1024;
    float invE = 1.f / (float)E;

    // ---- graph build ----
    k_init<<<gN, 256, 0, stream>>>(deg, meanbuf, N);
    k_count<<<gEt, 256, 0, stream>>>(dstrow, deg, rank, E, Et);
    k_mean<<<256, 256, 0, stream>>>(ea, meanbuf, E);
    k_scan_block<<<nb, 1024, 0, stream>>>(deg, rowptr, bsums, N);
    k_scan_bsums<<<1, 64, 0, stream>>>(bsums, boffs, nb);
    k_scan_finalize<<<gN, 256, 0, stream>>>(rowptr, boffs, N);
    k_fill<<<gEt, 256, 0, stream>>>(srcrow, dstrow, rowptr, rank, srcid, ea_csr, ea,
                                    meanbuf, invE, E, Et);

    // ---- weight + input preprocessing ----
    k_collapse<4><<<1, 512, 0, stream>>>(We1, att_e1, M1);
    k_collapse<1><<<1, 128, 0, stream>>>(We2, att_e2, M2);
    k_split_wT<<<256, 384, 0, stream>>>(W1, w1hT, w1lT, IN_DIM, 256, K1PAD);
    k_split_wT<<<64, 256, 0, stream>>>(W2, w2hT, w2lT, 256, 64, 256);
    k_split_a<<<N, 384, 0, stream>>>(x, xh, xl, IN_DIM, K1PAD);

    // ---- layer 1: GATConv(329 -> 64, heads=4) + ELU ----
    k_gemm_pre<4, 2><<<dim3(gM1, 4), 256, 0, stream>>>(xh, xl, w1hT, w1lT, h1h, h1l,
                                                       N, K1PAD, 256);
    k_node_attn2<4><<<N, 256, 0, stream>>>(h1h, h1l, att_src1, att_dst1, asrc, adst, N);
    k_attn<4><<<(N + 3) / 4, 256, 0, stream>>>(rowptr, srcid, ea_csr, asrc, adst, M1, attn, dinv, N);
    k_aggregate_planes<4><<<(N + 7) / 8, 256, 0, stream>>>(rowptr, srcid, attn, dinv,
                                                           h1h, b1, aggh, aggl, N);

    // ---- layer 2: GATConv(256 -> 64, heads=1), fc fused into aggregate ----
    k_gemm_pre<2, 2><<<dim3(gM2, 1), 256, 0, stream>>>(aggh, aggl, w2hT, w2lT, h2h, h2l,
                                                       N, 256, 64);
    k_node_attn2<1><<<(N + 3) / 4, 256, 0, stream>>>(h2h, h2l, att_src2, att_dst2, asrc, adst, N);
    k_attn<1><<<(N + 3) / 4, 256, 0, stream>>>(rowptr, srcid, ea_csr, asrc, adst, M2, attn, dinv, N);
    k_aggregate_fc<<<(N + 31) / 32, 256, 0, stream>>>(rowptr, srcid, attn, dinv,
                                                      h2h, b2, Wf, bf, (float*)d_out, N);
}